// Round 1
// baseline (108.091 us; speedup 1.0000x reference)
//
#include <hip/hip_runtime.h>

#define N_ATOMS 16384
#define NUM_BATCH 32
#define N_PAIRS 1048576
#define ATOMS_PER_BATCH 512
#define PAIRS_PER_THREAD 16

// ---- constants (double-computed, truncated to fp32) ----
#define C_TWO_PI 6.2831853071795864769f
#define C_ALPHA 0.401f                 // 4/10 + 0.001
#define C_ALPHA2 0.160801f             // 0.401^2
#define C_SELF 0.22624002f             // 0.401 / sqrt(pi)
#define C_EPS 1e-8f

// ---------------------------------------------------------------------------
// Real-space: each thread processes 16 consecutive (sorted-by-idx_i) pairs,
// run-merges equal idx_i locally, ~1 atomic per run boundary.
// ---------------------------------------------------------------------------
__device__ __forceinline__ float switch_fn(float r) {
    float x = (r - 2.5f) * 0.2f;   // (r - ON) / (OFF - ON), ON=2.5 OFF=7.5
    if (x <= 0.0f) return 1.0f;
    if (x >= 1.0f) return 0.0f;
    float fp = __expf(-1.0f / x);
    float fm = __expf(-1.0f / (1.0f - x));
    return fm / (fp + fm);
}

__global__ __launch_bounds__(256) void real_kernel(
    const float* __restrict__ Qa, const float* __restrict__ rij,
    const int* __restrict__ idx_i, const int* __restrict__ idx_j,
    float* __restrict__ out) {
    int t = blockIdx.x * blockDim.x + threadIdx.x;
    long base = (long)t * PAIRS_PER_THREAD;
    const int4*   ii4 = (const int4*)(idx_i + base);
    const int4*   jj4 = (const int4*)(idx_j + base);
    const float4* rr4 = (const float4*)(rij + base);

    int cur = -1;
    float acc = 0.0f;
#pragma unroll
    for (int g = 0; g < PAIRS_PER_THREAD / 4; ++g) {
        int4 ii = ii4[g];
        int4 jj = jj4[g];
        float4 rr = rr4[g];
        int   is[4] = {ii.x, ii.y, ii.z, ii.w};
        int   js[4] = {jj.x, jj.y, jj.z, jj.w};
        float rs[4] = {rr.x, rr.y, rr.z, rr.w};
#pragma unroll
        for (int u = 0; u < 4; ++u) {
            int i = is[u];
            float r = rs[u];
            float f = switch_fn(r);
            float coul   = __builtin_amdgcn_rcpf(r);
            float damped = __builtin_amdgcn_rsqf(fmaf(r, r, 1.0f));
            float fac = Qa[i] * Qa[js[u]];
            float pw = fac * (f * damped + (1.0f - f) * coul) * erfcf(C_ALPHA * r);
            if (i != cur) {
                if (cur >= 0) atomicAdd(out + cur, acc);
                cur = i;
                acc = 0.0f;
            }
            acc += pw;
        }
    }
    if (cur >= 0) atomicAdd(out + cur, acc);
}

// ---------------------------------------------------------------------------
// Reciprocal-space structure factor. Grid: (k-chunks, NUM_BATCH).
// Block: 64 (k-vectors) x 4 (atom split). Uses conjugate symmetry: only the
// second half of the lexicographic kmul list (one of each +/- pair), x2.
// ---------------------------------------------------------------------------
#define ASPLIT 4
#define AT_PER_SPLIT (ATOMS_PER_BATCH / ASPLIT)   // 128

__global__ __launch_bounds__(64 * ASPLIT) void recip_kernel(
    const float* __restrict__ Qa, const float* __restrict__ R,
    const float* __restrict__ cell, const float* __restrict__ kmul,
    float* __restrict__ e_recip_b, int K) {
    __shared__ float4 at[ATOMS_PER_BATCH];
    __shared__ float pr[ASPLIT][64];
    __shared__ float pi_[ASPLIT][64];

    int b  = blockIdx.y;
    int tx = threadIdx.x;          // k within chunk
    int ty = threadIdx.y;          // atom split
    int flat = ty * 64 + tx;

    float Lx = cell[b * 9 + 0], Ly = cell[b * 9 + 4], Lz = cell[b * 9 + 8];
    float iLx = 1.0f / Lx, iLy = 1.0f / Ly, iLz = 1.0f / Lz;

    // stage (R/L, q) for this batch's 512 atoms
    int abase = b * ATOMS_PER_BATCH;
    for (int a = flat; a < ATOMS_PER_BATCH; a += 64 * ASPLIT) {
        int n = abase + a;
        at[a] = make_float4(R[3 * n + 0] * iLx, R[3 * n + 1] * iLy,
                            R[3 * n + 2] * iLz, Qa[n]);
    }
    __syncthreads();

    int K2 = K >> 1;
    int kk = K2 + blockIdx.x * 64 + tx;
    bool valid = kk < K;
    int kki = valid ? kk : K2;
    float mx = kmul[3 * kki + 0];
    float my = kmul[3 * kki + 1];
    float mz = kmul[3 * kki + 2];

    float cr = 0.0f, ci = 0.0f;
    int a0 = ty * AT_PER_SPLIT;
#pragma unroll 4
    for (int a = a0; a < a0 + AT_PER_SPLIT; ++a) {
        float4 v = at[a];
        float dr = mx * v.x + my * v.y + mz * v.z;  // phase in revolutions
        float ang = C_TWO_PI * (dr - rintf(dr));    // [-pi, pi]
        float s = __sinf(ang);
        float c = __cosf(ang);
        cr = fmaf(v.w, c, cr);
        ci = fmaf(v.w, s, ci);
    }

    if (ty > 0) { pr[ty][tx] = cr; pi_[ty][tx] = ci; }
    __syncthreads();
    if (ty == 0) {
#pragma unroll
        for (int s = 1; s < ASPLIT; ++s) { cr += pr[s][tx]; ci += pi_[s][tx]; }
        float kx = C_TWO_PI * mx * iLx;
        float ky = C_TWO_PI * my * iLy;
        float kz = C_TWO_PI * mz * iLz;
        float k2 = kx * kx + ky * ky + kz * kz;
        float qg = __expf(-0.25f * k2 / C_ALPHA2) / k2;
        float contrib = valid ? 2.0f * (cr * cr + ci * ci) * qg : 0.0f;
#pragma unroll
        for (int off = 32; off > 0; off >>= 1)
            contrib += __shfl_down(contrib, off);
        if (tx == 0) {
            float scale = C_TWO_PI / (Lx * Ly * Lz);
            atomicAdd(e_recip_b + b, scale * contrib);
        }
    }
}

// ---------------------------------------------------------------------------
// Per-batch sum of (q^2 + eps)
// ---------------------------------------------------------------------------
__global__ __launch_bounds__(64) void wnorm_kernel(
    const float* __restrict__ Qa, float* __restrict__ wnorm) {
    int b = blockIdx.x;
    int tid = threadIdx.x;
    float s = 0.0f;
    for (int a = tid; a < ATOMS_PER_BATCH; a += 64) {
        float q = Qa[b * ATOMS_PER_BATCH + a];
        s = fmaf(q, q, s + C_EPS);
    }
#pragma unroll
    for (int off = 32; off > 0; off >>= 1) s += __shfl_down(s, off);
    if (tid == 0) wnorm[b] = s;
}

// ---------------------------------------------------------------------------
// Final combine: out[n] = e_real[n] + w[n]*e_recip_b[b] - self[n]
// ---------------------------------------------------------------------------
__global__ __launch_bounds__(256) void final_kernel(
    const float* __restrict__ Qa, const int* __restrict__ batch_seg,
    const float* __restrict__ e_recip_b, const float* __restrict__ wnorm,
    float* __restrict__ out) {
    int n = blockIdx.x * blockDim.x + threadIdx.x;
    if (n >= N_ATOMS) return;
    int b = batch_seg[n];
    float q = Qa[n];
    float q2 = q * q;
    float w = (q2 + C_EPS) / wnorm[b];
    out[n] = out[n] + w * e_recip_b[b] - C_SELF * q2;
}

extern "C" void kernel_launch(void* const* d_in, const int* in_sizes, int n_in,
                              void* d_out, int out_size, void* d_ws, size_t ws_size,
                              hipStream_t stream) {
    const float* Qa   = (const float*)d_in[0];
    const float* rij  = (const float*)d_in[1];
    const float* R    = (const float*)d_in[2];
    const float* cell = (const float*)d_in[3];
    const float* kmul = (const float*)d_in[4];
    const int* idx_i  = (const int*)d_in[5];
    const int* idx_j  = (const int*)d_in[6];
    const int* bseg   = (const int*)d_in[7];
    float* out = (float*)d_out;

    int K = in_sizes[4] / 3;       // number of k-vectors (even: closed under +/-)
    int K2 = K / 2;

    float* ws        = (float*)d_ws;
    float* e_recip_b = ws;         // [32]
    float* wnorm     = ws + 32;    // [32]

    hipMemsetAsync(d_out, 0, N_ATOMS * sizeof(float), stream);
    hipMemsetAsync(ws, 0, 64 * sizeof(float), stream);

    real_kernel<<<N_PAIRS / PAIRS_PER_THREAD / 256, 256, 0, stream>>>(
        Qa, rij, idx_i, idx_j, out);

    dim3 rblock(64, ASPLIT);
    dim3 rgrid((K2 + 63) / 64, NUM_BATCH);
    recip_kernel<<<rgrid, rblock, 0, stream>>>(Qa, R, cell, kmul, e_recip_b, K);

    wnorm_kernel<<<NUM_BATCH, 64, 0, stream>>>(Qa, wnorm);

    final_kernel<<<(N_ATOMS + 255) / 256, 256, 0, stream>>>(
        Qa, bseg, e_recip_b, wnorm, out);
}